// Round 5
// baseline (2400.996 us; speedup 1.0000x reference)
//
#include <hip/hip_runtime.h>

#define KD 64        // embedding dim
#define NPB 64       // nodes per bucket (bucket = dst >> 6)
#define SCAN_BLK 256

// ---------------- bucket build ----------------

// LDS-aggregated histogram of dst>>6 (NB counters, dynamic LDS)
__global__ void bhist_kernel(const int* __restrict__ dst, int* __restrict__ cntb,
                             int E, int NB) {
    extern __shared__ int lcnt[];
    for (int i = threadIdx.x; i < NB; i += blockDim.x) lcnt[i] = 0;
    __syncthreads();
    for (int i = blockIdx.x * blockDim.x + threadIdx.x; i < E; i += gridDim.x * blockDim.x)
        atomicAdd(&lcnt[dst[i] >> 6], 1);
    __syncthreads();
    for (int i = threadIdx.x; i < NB; i += blockDim.x) {
        int v = lcnt[i];
        if (v) atomicAdd(&cntb[i], v);
    }
}

// block-level exclusive scan; blk_sums gets per-block totals
__global__ void scan1_kernel(const int* __restrict__ cnt, int* __restrict__ optr,
                             int* __restrict__ blk_sums, int n) {
    __shared__ int s[SCAN_BLK];
    int t = threadIdx.x;
    int g = blockIdx.x * SCAN_BLK + t;
    int v = (g < n) ? cnt[g] : 0;
    s[t] = v;
    __syncthreads();
    for (int off = 1; off < SCAN_BLK; off <<= 1) {
        int add = (t >= off) ? s[t - off] : 0;
        __syncthreads();
        s[t] += add;
        __syncthreads();
    }
    if (g < n) optr[g] = s[t] - v;               // exclusive
    if (t == SCAN_BLK - 1) blk_sums[blockIdx.x] = s[t];
}

__global__ void scan2_kernel(int* __restrict__ blk_sums, int nblk) {
    __shared__ int s[1024];
    int t = threadIdx.x;
    int v = (t < nblk) ? blk_sums[t] : 0;
    s[t] = v;
    __syncthreads();
    for (int off = 1; off < 1024; off <<= 1) {
        int add = (t >= off) ? s[t - off] : 0;
        __syncthreads();
        s[t] += add;
        __syncthreads();
    }
    if (t < nblk) blk_sums[t] = s[t] - v;        // exclusive
}

// finalize bucket ptr, init cursor
__global__ void scan3b_kernel(int* __restrict__ bptr, const int* __restrict__ blk_sums,
                              int* __restrict__ cursor, int NB, int E) {
    int g = blockIdx.x * 256 + threadIdx.x;
    if (g < NB) {
        int v = bptr[g] + blk_sums[g >> 8];
        bptr[g] = v;
        cursor[g] = v;
    }
    if (g == 0) bptr[NB] = E;
}

// partition: staged[cursor[dst>>6]++] = src | (dst&63)<<18
__global__ void part_kernel(const int* __restrict__ src, const int* __restrict__ dst,
                            int* __restrict__ cursor, unsigned int* __restrict__ staged,
                            int E) {
    for (int e = blockIdx.x * blockDim.x + threadIdx.x; e < E; e += gridDim.x * blockDim.x) {
        int d = dst[e];
        int p = atomicAdd(&cursor[d >> 6], 1);
        staged[p] = (unsigned int)src[e] | (((unsigned int)d & 63u) << 18);
    }
}

// per-bucket in-degree -> r[node] = rsqrt(max(deg,1))
__global__ __launch_bounds__(256)
void bucketr_kernel(const unsigned int* __restrict__ staged, const int* __restrict__ bptr,
                    float* __restrict__ r, int n_nodes) {
    __shared__ int lcnt[NPB];
    int b = blockIdx.x;
    if (threadIdx.x < NPB) lcnt[threadIdx.x] = 0;
    __syncthreads();
    int begin = bptr[b], end = bptr[b + 1];
    for (int i = begin + threadIdx.x; i < end; i += blockDim.x)
        atomicAdd(&lcnt[(staged[i] >> 18) & 63u], 1);
    __syncthreads();
    if (threadIdx.x < NPB) {
        int node = b * NPB + threadIdx.x;
        if (node < n_nodes)
            r[node] = rsqrtf(fmaxf((float)lcnt[threadIdx.x], 1.0f));
    }
}

// ---------------- embedding kernels ----------------

// x0 = (Gu+Gut | Gi+Git); out = x0; xs = x0 * r[node]  (all f32)
__global__ void combine_kernel(const float4* __restrict__ Gu, const float4* __restrict__ Gi,
                               const float4* __restrict__ Gut, const float4* __restrict__ Git,
                               const float* __restrict__ r,
                               float4* __restrict__ out, float4* __restrict__ xs,
                               int nu4, int total4) {
    for (int i = blockIdx.x * blockDim.x + threadIdx.x; i < total4; i += gridDim.x * blockDim.x) {
        float4 a, b;
        if (i < nu4) { a = Gu[i]; b = Gut[i]; }
        else         { a = Gi[i - nu4]; b = Git[i - nu4]; }
        float4 c;
        c.x = a.x + b.x; c.y = a.y + b.y; c.z = a.z + b.z; c.w = a.w + b.w;
        out[i] = c;
        float rr = r[i >> 4];   // 16 float4 per node row
        float4 sc;
        sc.x = c.x * rr; sc.y = c.y * rr; sc.z = c.z * rr; sc.w = c.w * rr;
        xs[i] = sc;
    }
}

// one workgroup per bucket; 64x64 f32 LDS accumulator (16KB, stride 64 -> 2-way
// bank aliasing = free). Each wave: 4 edges/iter, 4 independent 256B row loads
// (lane = dim), then 4 LDS atomic adds. Epilogue: y = acc*r; out += alpha*y;
// xs_next = y*r (skip on last layer).
__global__ __launch_bounds__(256)
void gatherb_kernel(const unsigned int* __restrict__ staged, const int* __restrict__ bptr,
                    const float* __restrict__ r, const float* __restrict__ xs,
                    float* __restrict__ out, float* __restrict__ xs_next,
                    float alpha, int n_nodes, int last) {
    __shared__ float acc[NPB * KD];
    int b = blockIdx.x;
    int tid = threadIdx.x;
    for (int i = tid; i < NPB * KD; i += 256) acc[i] = 0.f;
    __syncthreads();

    int lane = tid & 63;
    int w = tid >> 6;                       // wave 0..3
    int begin = bptr[b], end = bptr[b + 1];

    for (int e = begin + w * 4; e < end; e += 16) {
        int n = end - e;                    // >= 1, wave-uniform
        unsigned int p0 = staged[e];
        unsigned int p1 = staged[(n > 1) ? e + 1 : e];
        unsigned int p2 = staged[(n > 2) ? e + 2 : e];
        unsigned int p3 = staged[(n > 3) ? e + 3 : e];
        float v0 = xs[(p0 & 0x3FFFFu) * KD + lane];
        float v1 = xs[(p1 & 0x3FFFFu) * KD + lane];
        float v2 = xs[(p2 & 0x3FFFFu) * KD + lane];
        float v3 = xs[(p3 & 0x3FFFFu) * KD + lane];
        atomicAdd(&acc[((p0 >> 18) & 63u) * KD + lane], v0);
        if (n > 1) atomicAdd(&acc[((p1 >> 18) & 63u) * KD + lane], v1);
        if (n > 2) atomicAdd(&acc[((p2 >> 18) & 63u) * KD + lane], v2);
        if (n > 3) atomicAdd(&acc[((p3 >> 18) & 63u) * KD + lane], v3);
    }
    __syncthreads();

    for (int local = w; local < NPB; local += 4) {
        int node = b * NPB + local;
        if (node >= n_nodes) break;
        float rr = r[node];
        float y = acc[local * KD + lane] * rr;
        int idx = node * KD + lane;
        out[idx] += alpha * y;
        if (!last) xs_next[idx] = y * rr;
    }
}

// ---------------- launch ----------------

extern "C" void kernel_launch(void* const* d_in, const int* in_sizes, int n_in,
                              void* d_out, int out_size, void* d_ws, size_t ws_size,
                              hipStream_t stream) {
    const float* Gu  = (const float*)d_in[0];
    const float* Gi  = (const float*)d_in[1];
    const float* Gut = (const float*)d_in[2];
    const float* Git = (const float*)d_in[3];
    const int*   edge_index = (const int*)d_in[4];
    const int n_layers = 3;

    const int nuK = in_sizes[0];
    const int niK = in_sizes[1];
    const int n_nodes = (nuK + niK) / KD;       // 150000
    const int E = in_sizes[4] / 2;              // 2,000,000
    const int totalK = nuK + niK;
    const int total4 = totalK / 4;
    const int nu4 = nuK / 4;
    const int NB = (n_nodes + NPB - 1) / NPB;   // 2344 buckets

    const int* src = edge_index;
    const int* dst = edge_index + E;

    auto align_up = [](size_t v) { return (v + 255) & ~(size_t)255; };
    char* ws = (char*)d_ws;
    size_t off = 0;
    int*          cntb     = (int*)(ws + off);          off += align_up((size_t)NB * 4);
    int*          bptr     = (int*)(ws + off);          off += align_up((size_t)(NB + 1) * 4);
    int*          blk_sums = (int*)(ws + off);          off += align_up((size_t)1024 * 4);
    int*          cursor   = (int*)(ws + off);          off += align_up((size_t)NB * 4);
    float*        r        = (float*)(ws + off);        off += align_up((size_t)n_nodes * 4);
    unsigned int* staged   = (unsigned int*)(ws + off); off += align_up((size_t)E * 4);
    float*        xsA      = (float*)(ws + off);        off += align_up((size_t)totalK * 4);
    float*        xsB      = (float*)(ws + off);        off += align_up((size_t)totalK * 4);
    if (off > ws_size) return;

    float* out = (float*)d_out;

    const int BLK = 256;
    const int grid_e = 2048;
    const int grid_v = 2048;
    const int nblkB = (NB + SCAN_BLK - 1) / SCAN_BLK;   // 10
    const int grid_nb = (NB + 255) / 256;

    // bucket partition build
    hipMemsetAsync(cntb, 0, (size_t)NB * 4, stream);
    bhist_kernel<<<256, BLK, (size_t)NB * 4, stream>>>(dst, cntb, E, NB);
    scan1_kernel<<<nblkB, SCAN_BLK, 0, stream>>>(cntb, bptr, blk_sums, NB);
    scan2_kernel<<<1, 1024, 0, stream>>>(blk_sums, nblkB);
    scan3b_kernel<<<grid_nb, 256, 0, stream>>>(bptr, blk_sums, cursor, NB, E);
    part_kernel<<<grid_e, BLK, 0, stream>>>(src, dst, cursor, staged, E);
    bucketr_kernel<<<NB, BLK, 0, stream>>>(staged, bptr, r, n_nodes);

    // x0 combine + pre-scale
    combine_kernel<<<grid_v, BLK, 0, stream>>>((const float4*)Gu, (const float4*)Gi,
                                               (const float4*)Gut, (const float4*)Git,
                                               r, (float4*)out, (float4*)xsA, nu4, total4);

    // propagation
    float* xcur = xsA;
    float* xnxt = xsB;
    for (int k = 0; k < n_layers; ++k) {
        float alpha = 1.0f / (float)(k + 2);
        int last = (k == n_layers - 1) ? 1 : 0;
        gatherb_kernel<<<NB, BLK, 0, stream>>>(staged, bptr, r, xcur,
                                               out, xnxt, alpha, n_nodes, last);
        float* t = xcur; xcur = xnxt; xnxt = t;
    }
}

// Round 6
// 523.081 us; speedup vs baseline: 4.5901x; 4.5901x over previous
//
#include <hip/hip_runtime.h>

#define KD 64        // embedding dim
#define NPB 64       // nodes per bucket (bucket = dst >> 6)
#define SCAN_BLK 256

// ---------------- bucket build ----------------

// LDS-aggregated histogram of dst>>6 (NB counters, dynamic LDS)
__global__ void bhist_kernel(const int* __restrict__ dst, int* __restrict__ cntb,
                             int E, int NB) {
    extern __shared__ int lcnt[];
    for (int i = threadIdx.x; i < NB; i += blockDim.x) lcnt[i] = 0;
    __syncthreads();
    for (int i = blockIdx.x * blockDim.x + threadIdx.x; i < E; i += gridDim.x * blockDim.x)
        atomicAdd(&lcnt[dst[i] >> 6], 1);
    __syncthreads();
    for (int i = threadIdx.x; i < NB; i += blockDim.x) {
        int v = lcnt[i];
        if (v) atomicAdd(&cntb[i], v);
    }
}

// block-level exclusive scan; blk_sums gets per-block totals
__global__ void scan1_kernel(const int* __restrict__ cnt, int* __restrict__ optr,
                             int* __restrict__ blk_sums, int n) {
    __shared__ int s[SCAN_BLK];
    int t = threadIdx.x;
    int g = blockIdx.x * SCAN_BLK + t;
    int v = (g < n) ? cnt[g] : 0;
    s[t] = v;
    __syncthreads();
    for (int off = 1; off < SCAN_BLK; off <<= 1) {
        int add = (t >= off) ? s[t - off] : 0;
        __syncthreads();
        s[t] += add;
        __syncthreads();
    }
    if (g < n) optr[g] = s[t] - v;               // exclusive
    if (t == SCAN_BLK - 1) blk_sums[blockIdx.x] = s[t];
}

__global__ void scan2_kernel(int* __restrict__ blk_sums, int nblk) {
    __shared__ int s[1024];
    int t = threadIdx.x;
    int v = (t < nblk) ? blk_sums[t] : 0;
    s[t] = v;
    __syncthreads();
    for (int off = 1; off < 1024; off <<= 1) {
        int add = (t >= off) ? s[t - off] : 0;
        __syncthreads();
        s[t] += add;
        __syncthreads();
    }
    if (t < nblk) blk_sums[t] = s[t] - v;        // exclusive
}

// finalize bucket ptr, init cursor
__global__ void scan3b_kernel(int* __restrict__ bptr, const int* __restrict__ blk_sums,
                              int* __restrict__ cursor, int NB, int E) {
    int g = blockIdx.x * 256 + threadIdx.x;
    if (g < NB) {
        int v = bptr[g] + blk_sums[g >> 8];
        bptr[g] = v;
        cursor[g] = v;
    }
    if (g == 0) bptr[NB] = E;
}

// partition: staged[cursor[dst>>6]++] = src | (dst&63)<<18
__global__ void part_kernel(const int* __restrict__ src, const int* __restrict__ dst,
                            int* __restrict__ cursor, unsigned int* __restrict__ staged,
                            int E) {
    for (int e = blockIdx.x * blockDim.x + threadIdx.x; e < E; e += gridDim.x * blockDim.x) {
        int d = dst[e];
        int p = atomicAdd(&cursor[d >> 6], 1);
        staged[p] = (unsigned int)src[e] | (((unsigned int)d & 63u) << 18);
    }
}

// per-bucket exact counting sort (writes stay inside the bucket's contiguous
// window of sorted_src -> L2-merged). Also emits row_ptr and r for its 64 nodes.
__global__ __launch_bounds__(256)
void bsort_kernel(const unsigned int* __restrict__ staged, const int* __restrict__ bptr,
                  int* __restrict__ sorted_src, int* __restrict__ row_ptr,
                  float* __restrict__ r, int n_nodes, int NB, int E) {
    __shared__ int lcnt[NPB];
    __shared__ int lofs[NPB];
    int b = blockIdx.x;
    int tid = threadIdx.x;
    if (tid < NPB) lcnt[tid] = 0;
    __syncthreads();
    int begin = bptr[b], end = bptr[b + 1];
    // pass 1: per-node counts
    for (int i = begin + tid; i < end; i += 256)
        atomicAdd(&lcnt[(staged[i] >> 18) & 63u], 1);
    __syncthreads();
    // exclusive scan of 64 counters (wave 0, lanes 0..63 via shfl_up)
    if (tid < 64) {
        int v = lcnt[tid];
        int s = v;
        for (int off = 1; off < 64; off <<= 1) {
            int u = __shfl_up(s, off);
            if ((tid & 63) >= off) s += u;
        }
        lofs[tid] = s - v;                       // exclusive
        int node = b * NPB + tid;
        if (node < n_nodes) {
            row_ptr[node] = begin + (s - v);
            r[node] = rsqrtf(fmaxf((float)v, 1.0f));
        }
        lcnt[tid] = 0;                           // reuse as cursor
    }
    if (b == 0 && tid == 0) row_ptr[n_nodes] = E;
    __syncthreads();
    // pass 2: scatter within bucket window
    for (int i = begin + tid; i < end; i += 256) {
        unsigned int u = staged[i];
        int ld = (u >> 18) & 63u;
        int p = begin + lofs[ld] + atomicAdd(&lcnt[ld], 1);
        sorted_src[p] = (int)(u & 0x3FFFFu);
    }
}

// ---------------- embedding kernels ----------------

// x0 = (Gu+Gut | Gi+Git); out = x0; xs = x0 * r[node]  (all f32)
__global__ void combine_kernel(const float4* __restrict__ Gu, const float4* __restrict__ Gi,
                               const float4* __restrict__ Gut, const float4* __restrict__ Git,
                               const float* __restrict__ r,
                               float4* __restrict__ out, float4* __restrict__ xs,
                               int nu4, int total4) {
    for (int i = blockIdx.x * blockDim.x + threadIdx.x; i < total4; i += gridDim.x * blockDim.x) {
        float4 a, b;
        if (i < nu4) { a = Gu[i]; b = Gut[i]; }
        else         { a = Gi[i - nu4]; b = Git[i - nu4]; }
        float4 c;
        c.x = a.x + b.x; c.y = a.y + b.y; c.z = a.z + b.z; c.w = a.w + b.w;
        out[i] = c;
        float rr = r[i >> 4];   // 16 float4 per node row
        float4 sc;
        sc.x = c.x * rr; sc.y = c.y * rr; sc.z = c.z * rr; sc.w = c.w * rr;
        xs[i] = sc;
    }
}

// one wave per dst node; 4 subgroups x 16 lanes; each subgroup processes 4 edges
// per iteration with 4 INDEPENDENT float4 loads issued before accumulation.
// y = acc * r; out += alpha*y; xs_next = y * r (skip on last layer).
__global__ __launch_bounds__(256)
void gather_kernel(const int* __restrict__ row_ptr, const int* __restrict__ sorted_src,
                   const float* __restrict__ r, const float4* __restrict__ xs,
                   float4* __restrict__ out, float4* __restrict__ xs_next,
                   float alpha, int N, int last) {
    int wid = (blockIdx.x * blockDim.x + threadIdx.x) >> 6;
    int lane = threadIdx.x & 63;
    if (wid >= N) return;
    int start = row_ptr[wid];
    int end   = row_ptr[wid + 1];
    int sub = lane >> 4;      // edge subgroup 0..3
    int li  = lane & 15;      // float4 slot within the 64-dim row

    float ax = 0.f, ay = 0.f, az = 0.f, aw = 0.f;
    for (int base = start; base < end; base += 64) {
        int nb = end - base; if (nb > 64) nb = 64;
        int eaddr = base + lane;
        int laste = end - 1;
        if (eaddr > laste) eaddr = laste;
        int es = sorted_src[eaddr];              // 64 edge ids (clamped tail)
        for (int c = 0; c < nb; c += 16) {
            int j0 = c + sub * 4;
            int s0 = __shfl(es, j0 + 0);
            int s1 = __shfl(es, j0 + 1);
            int s2 = __shfl(es, j0 + 2);
            int s3 = __shfl(es, j0 + 3);
            if (j0 < nb) {
                float m0 = 1.f;
                float m1 = (j0 + 1 < nb) ? 1.f : 0.f;
                float m2 = (j0 + 2 < nb) ? 1.f : 0.f;
                float m3 = (j0 + 3 < nb) ? 1.f : 0.f;
                float4 v0 = xs[s0 * 16 + li];
                float4 v1 = xs[s1 * 16 + li];
                float4 v2 = xs[s2 * 16 + li];
                float4 v3 = xs[s3 * 16 + li];
                ax += m0 * v0.x + m1 * v1.x + m2 * v2.x + m3 * v3.x;
                ay += m0 * v0.y + m1 * v1.y + m2 * v2.y + m3 * v3.y;
                az += m0 * v0.z + m1 * v1.z + m2 * v2.z + m3 * v3.z;
                aw += m0 * v0.w + m1 * v1.w + m2 * v2.w + m3 * v3.w;
            }
        }
    }
    ax += __shfl_xor(ax, 16); ay += __shfl_xor(ay, 16);
    az += __shfl_xor(az, 16); aw += __shfl_xor(aw, 16);
    ax += __shfl_xor(ax, 32); ay += __shfl_xor(ay, 32);
    az += __shfl_xor(az, 32); aw += __shfl_xor(aw, 32);

    if (lane < 16) {
        float rr = r[wid];
        float yx = ax * rr, yy = ay * rr, yz = az * rr, yw = aw * rr;
        int idx = wid * 16 + lane;
        float4 o = out[idx];
        o.x += alpha * yx; o.y += alpha * yy; o.z += alpha * yz; o.w += alpha * yw;
        out[idx] = o;
        if (!last) {
            float4 p;
            p.x = yx * rr; p.y = yy * rr; p.z = yz * rr; p.w = yw * rr;
            xs_next[idx] = p;
        }
    }
}

// ---------------- launch ----------------

extern "C" void kernel_launch(void* const* d_in, const int* in_sizes, int n_in,
                              void* d_out, int out_size, void* d_ws, size_t ws_size,
                              hipStream_t stream) {
    const float* Gu  = (const float*)d_in[0];
    const float* Gi  = (const float*)d_in[1];
    const float* Gut = (const float*)d_in[2];
    const float* Git = (const float*)d_in[3];
    const int*   edge_index = (const int*)d_in[4];
    const int n_layers = 3;

    const int nuK = in_sizes[0];
    const int niK = in_sizes[1];
    const int n_nodes = (nuK + niK) / KD;       // 150000
    const int E = in_sizes[4] / 2;              // 2,000,000
    const int totalK = nuK + niK;
    const int total4 = totalK / 4;
    const int nu4 = nuK / 4;
    const int NB = (n_nodes + NPB - 1) / NPB;   // 2344 buckets

    const int* src = edge_index;
    const int* dst = edge_index + E;

    auto align_up = [](size_t v) { return (v + 255) & ~(size_t)255; };
    char* ws = (char*)d_ws;
    size_t off = 0;
    int*          cntb       = (int*)(ws + off);          off += align_up((size_t)NB * 4);
    int*          bptr       = (int*)(ws + off);          off += align_up((size_t)(NB + 1) * 4);
    int*          blk_sums   = (int*)(ws + off);          off += align_up((size_t)1024 * 4);
    int*          cursor     = (int*)(ws + off);          off += align_up((size_t)NB * 4);
    int*          row_ptr    = (int*)(ws + off);          off += align_up((size_t)(n_nodes + 1) * 4);
    float*        r          = (float*)(ws + off);        off += align_up((size_t)n_nodes * 4);
    unsigned int* staged     = (unsigned int*)(ws + off); off += align_up((size_t)E * 4);
    int*          sorted_src = (int*)(ws + off);          off += align_up((size_t)E * 4);
    float*        xsA        = (float*)(ws + off);        off += align_up((size_t)totalK * 4);
    float*        xsB        = (float*)(ws + off);        off += align_up((size_t)totalK * 4);
    if (off > ws_size) return;

    float* out = (float*)d_out;

    const int BLK = 256;
    const int grid_e = 2048;
    const int grid_v = 2048;
    const int nblkB = (NB + SCAN_BLK - 1) / SCAN_BLK;   // 10
    const int grid_nb = (NB + 255) / 256;
    const int grid_g = (n_nodes * KD + BLK - 1) / BLK;  // 1 wave/node

    // bucket partition + exact per-bucket sort
    hipMemsetAsync(cntb, 0, (size_t)NB * 4, stream);
    bhist_kernel<<<256, BLK, (size_t)NB * 4, stream>>>(dst, cntb, E, NB);
    scan1_kernel<<<nblkB, SCAN_BLK, 0, stream>>>(cntb, bptr, blk_sums, NB);
    scan2_kernel<<<1, 1024, 0, stream>>>(blk_sums, nblkB);
    scan3b_kernel<<<grid_nb, 256, 0, stream>>>(bptr, blk_sums, cursor, NB, E);
    part_kernel<<<grid_e, BLK, 0, stream>>>(src, dst, cursor, staged, E);
    bsort_kernel<<<NB, BLK, 0, stream>>>(staged, bptr, sorted_src, row_ptr, r,
                                         n_nodes, NB, E);

    // x0 combine + pre-scale
    combine_kernel<<<grid_v, BLK, 0, stream>>>((const float4*)Gu, (const float4*)Gi,
                                               (const float4*)Gut, (const float4*)Git,
                                               r, (float4*)out, (float4*)xsA, nu4, total4);

    // propagation
    float* xcur = xsA;
    float* xnxt = xsB;
    for (int k = 0; k < n_layers; ++k) {
        float alpha = 1.0f / (float)(k + 2);
        int last = (k == n_layers - 1) ? 1 : 0;
        gather_kernel<<<grid_g, BLK, 0, stream>>>(row_ptr, sorted_src, r,
                                                  (const float4*)xcur,
                                                  (float4*)out, (float4*)xnxt,
                                                  alpha, n_nodes, last);
        float* t = xcur; xcur = xnxt; xnxt = t;
    }
}